// Round 5
// baseline (237.514 us; speedup 1.0000x reference)
//
#include <hip/hip_runtime.h>
#include <math.h>

#define N_PRED  12
#define N_DRIFT 2
#define N_DW    3
#define N_NODES 4096
#define BB      128
#define BN      (BB * N_NODES)     // 524288 pairs
#define NTILES  (BN / 16)          // 32768 row-tiles of 16 pairs
#define RPW     4                  // row-tiles per wave (pipelined)
#define WPB     4                  // waves per block (256 thr)
#define NBLK    (NTILES / (RPW * WPB))   // 2048 blocks

typedef __attribute__((ext_vector_type(8))) short bf16x8;
typedef __attribute__((ext_vector_type(4))) float f32x4;

static __device__ __forceinline__ unsigned short bf16_rne(float f) {
    unsigned int u = __float_as_uint(f);
    u = (u + 0x7FFFu + ((u >> 16) & 1u)) >> 16;
    return (unsigned short)u;
}
static __device__ __forceinline__ float bf16_to_f32(unsigned short h) {
    return __uint_as_float(((unsigned int)h) << 16);
}

// ---------------------------------------------------------------------------
// BW probe: fill-kernel-shaped streaming read of inp (24 independent float4
// loads/thread, grid-stride layout). Sinks partial sums into d_out, which
// deform_main fully overwrites afterwards -> harmless. Purpose: measure
// achievable read BW in this exact harness context (vs 6.8 TB/s fill).
// ---------------------------------------------------------------------------
__global__ __launch_bounds__(256) void bw_probe(const float4* __restrict__ in4,
                                                float* __restrict__ sink) {
    const int gid = blockIdx.x * 256 + threadIdx.x;   // 262144 threads
    const size_t stride = 256 * 1024;                 // threads total
    float4 acc = make_float4(0.f, 0.f, 0.f, 0.f);
    #pragma unroll
    for (int i = 0; i < 24; ++i) {                    // 24*262144 = 6291456
        float4 v = in4[(size_t)i * stride + gid];
        acc.x += v.x; acc.y += v.y; acc.z += v.z; acc.w += v.w;
    }
    sink[gid] = acc.x + acc.y + acc.z + acc.w;
}

// ---------------------------------------------------------------------------
// Precompute (unchanged from R4, verified): folded uniform matrix M[64][48]
// emitted as bf16 hi/lo MFMA B-fragments. 12288 B into d_ws.
// ---------------------------------------------------------------------------
__global__ void deform_precompute(const float* __restrict__ offset_t,
                                  const float* __restrict__ offset_n,
                                  const float* __restrict__ conv_t_w,
                                  const float* __restrict__ conv_t_b,
                                  const float* __restrict__ conv_n_w,
                                  const float* __restrict__ conv_n_b,
                                  const float* __restrict__ W,
                                  unsigned short* __restrict__ wsB) {
    __shared__ float Ms[64][48];
    const int t = threadIdx.x;   // 256 threads

    auto coef = [&](const float* off, int kw, int c, int l) -> float {
        float pos = tanhf(off[kw * N_PRED + c]) * (float)N_DRIFT
                    + (float)(c + N_DRIFT);
        float idf = floorf(pos);
        float fr  = pos - idf;
        int   id  = (int)idf;
        if (l == id)     return 1.0f - fr;
        if (l == id + 1) return fr;
        return 0.0f;
    };

    for (int e = t; e < 64 * 48; e += 256) {
        int k = e / 48, col = e % 48;
        float v = 0.0f;
        if (k < 48) {
            int kw = k >> 4, l = k & 15;
            if (col < 12) {                       // Mt
                #pragma unroll
                for (int h = 0; h < 3; ++h) {
                    int c = col - 1 + h;
                    if (c < 0 || c >= N_PRED) continue;
                    v += conv_t_w[kw * 3 + h] * coef(offset_t, kw, c, l);
                }
            } else if (col >= 16 && col < 28) {   // Mn
                int q = col - 16;
                for (int c = 0; c < N_PRED; ++c)
                    v += conv_n_w[q * (N_PRED * N_DW) + c * N_DW + kw]
                         * coef(offset_n, kw, c, l);
            }
        } else if (k < 60) {                      // gate W rows
            if (col >= 32 && col < 44) v = W[(k - 48) * N_PRED + (col - 32)];
        } else if (k == 60) {                     // bias row (z = 1)
            if (col < 12)                 v = conv_t_b[0];
            else if (col >= 16 && col < 28) v = conv_n_b[col - 16];
        }
        Ms[k][col] = v;
    }
    __syncthreads();

    for (int e = t; e < 3 * 2 * 64 * 8; e += 256) {
        int j    = e & 7;
        int lane = (e >> 3) & 63;
        int kh   = (e >> 9) & 1;
        int ct   = e >> 10;
        int k    = kh * 32 + ((lane >> 4) << 3) + j;
        int col  = (lane & 15) + 16 * ct;
        float v  = Ms[k][col];
        unsigned short hi = bf16_rne(v);
        unsigned short lo = bf16_rne(v - bf16_to_f32(hi));
        int off_hi = ((ct * 2 + kh) * 2) * 512 + lane * 8 + j;
        wsB[off_hi]       = hi;
        wsB[off_hi + 512] = lo;
    }
}

// ---------------------------------------------------------------------------
// Main kernel, R5: R4's MFMA structure + explicit 1-deep software pipeline.
// Iteration r+1's global loads (x slab, ctrl, bparam) are issued BEFORE
// iteration r's pack/MFMA/epilogue -> each wave keeps >=5 loads in flight
// during compute (R4 drained per-iteration: serial chain, the suspected
// ~60 us binder).
// ---------------------------------------------------------------------------
__global__ __launch_bounds__(256, 3) void deform_main(
        const float* __restrict__ inp,      // (BN, 48)
        const float* __restrict__ ctrl,     // (BN, 12)
        const float* __restrict__ bparam,   // (N_NODES, 12)
        const unsigned short* __restrict__ wsB,
        float* __restrict__ out) {          // (BN, 12)
    const int lane = threadIdx.x & 63;
    const int wid  = blockIdx.x * WPB + (threadIdx.x >> 6);
    const int quad = lane >> 4;
    const int col  = lane & 15;

    // ---- B fragments: loop-invariant VGPR residents ----
    bf16x8 Bh[3][2], Bl[3][2];
    #pragma unroll
    for (int ct = 0; ct < 3; ++ct) {
        #pragma unroll
        for (int kh = 0; kh < 2; ++kh) {
            const bf16x8* ph =
                (const bf16x8*)(wsB + ((ct * 2 + kh) * 2) * 512);
            Bh[ct][kh] = ph[lane];
            Bl[ct][kh] = ph[lane + 64];
        }
    }

    const bool active = (col < 12);
    const int  bcol   = active ? col : 11;
    const int  rt0    = wid * RPW;

    // issue all global loads for row-tile rt into the given registers
    auto issue = [&](int rt, float4& A0, float4& A1, float4& B0, float4& B1,
                     float (&BP)[4]) {
        const int base_pair = rt * 16;
        const int pair      = base_pair + col;
        const float4* xp = (const float4*)(inp + (size_t)pair * 48 + quad * 8);
        A0 = xp[0];
        A1 = xp[1];
        const float* bbase;
        if (quad < 2)       bbase = inp  + (size_t)pair * 48 + 32 + quad * 8;
        else if (quad == 2) bbase = ctrl + (size_t)pair * 12;
        else                bbase = ctrl + (size_t)pair * 12 + 8;
        B0 = *(const float4*)bbase;
        if (quad == 3) B1 = make_float4(1.0f, 0.0f, 0.0f, 0.0f);
        else           B1 = *((const float4*)bbase + 1);
        #pragma unroll
        for (int i = 0; i < 4; ++i) {
            int prow = base_pair + quad * 4 + i;
            int n    = prow & (N_NODES - 1);
            BP[i] = bparam[n * N_PRED + bcol];
        }
    };

    float4 a0, a1, b0, b1, na0, na1, nb0, nb1;
    float  bp[4], nbp[4];
    issue(rt0, a0, a1, b0, b1, bp);

    #pragma unroll
    for (int r = 0; r < RPW; ++r) {
        // ---- prefetch next iteration before consuming current ----
        if (r + 1 < RPW) issue(rt0 + r + 1, na0, na1, nb0, nb1, nbp);

        const int base_pair = (rt0 + r) * 16;

        // ---- split current x/ctrl into bf16 hi/lo A-fragments ----
        float za[8] = {a0.x, a0.y, a0.z, a0.w, a1.x, a1.y, a1.z, a1.w};
        float zb[8] = {b0.x, b0.y, b0.z, b0.w, b1.x, b1.y, b1.z, b1.w};
        union { bf16x8 v; unsigned short u[8]; } Ah0, Al0, Ah1, Al1;
        #pragma unroll
        for (int j = 0; j < 8; ++j) {
            unsigned short h0 = bf16_rne(za[j]);
            Ah0.u[j] = h0;
            Al0.u[j] = bf16_rne(za[j] - bf16_to_f32(h0));
            unsigned short h1 = bf16_rne(zb[j]);
            Ah1.u[j] = h1;
            Al1.u[j] = bf16_rne(zb[j] - bf16_to_f32(h1));
        }

        // ---- 18 MFMAs ----
        f32x4 C0 = {0.f, 0.f, 0.f, 0.f}, C1 = C0, C2 = C0;
        C0 = __builtin_amdgcn_mfma_f32_16x16x32_bf16(Ah0.v, Bh[0][0], C0, 0, 0, 0);
        C0 = __builtin_amdgcn_mfma_f32_16x16x32_bf16(Ah1.v, Bh[0][1], C0, 0, 0, 0);
        C0 = __builtin_amdgcn_mfma_f32_16x16x32_bf16(Ah0.v, Bl[0][0], C0, 0, 0, 0);
        C0 = __builtin_amdgcn_mfma_f32_16x16x32_bf16(Ah1.v, Bl[0][1], C0, 0, 0, 0);
        C0 = __builtin_amdgcn_mfma_f32_16x16x32_bf16(Al0.v, Bh[0][0], C0, 0, 0, 0);
        C0 = __builtin_amdgcn_mfma_f32_16x16x32_bf16(Al1.v, Bh[0][1], C0, 0, 0, 0);

        C1 = __builtin_amdgcn_mfma_f32_16x16x32_bf16(Ah0.v, Bh[1][0], C1, 0, 0, 0);
        C1 = __builtin_amdgcn_mfma_f32_16x16x32_bf16(Ah1.v, Bh[1][1], C1, 0, 0, 0);
        C1 = __builtin_amdgcn_mfma_f32_16x16x32_bf16(Ah0.v, Bl[1][0], C1, 0, 0, 0);
        C1 = __builtin_amdgcn_mfma_f32_16x16x32_bf16(Ah1.v, Bl[1][1], C1, 0, 0, 0);
        C1 = __builtin_amdgcn_mfma_f32_16x16x32_bf16(Al0.v, Bh[1][0], C1, 0, 0, 0);
        C1 = __builtin_amdgcn_mfma_f32_16x16x32_bf16(Al1.v, Bh[1][1], C1, 0, 0, 0);

        C2 = __builtin_amdgcn_mfma_f32_16x16x32_bf16(Ah0.v, Bh[2][0], C2, 0, 0, 0);
        C2 = __builtin_amdgcn_mfma_f32_16x16x32_bf16(Ah1.v, Bh[2][1], C2, 0, 0, 0);
        C2 = __builtin_amdgcn_mfma_f32_16x16x32_bf16(Ah0.v, Bl[2][0], C2, 0, 0, 0);
        C2 = __builtin_amdgcn_mfma_f32_16x16x32_bf16(Ah1.v, Bl[2][1], C2, 0, 0, 0);
        C2 = __builtin_amdgcn_mfma_f32_16x16x32_bf16(Al0.v, Bh[2][0], C2, 0, 0, 0);
        C2 = __builtin_amdgcn_mfma_f32_16x16x32_bf16(Al1.v, Bh[2][1], C2, 0, 0, 0);

        // ---- epilogue: gate + blend + store ----
        #pragma unroll
        for (int i = 0; i < 4; ++i) {
            int prow = base_pair + quad * 4 + i;
            float g  = 1.0f / (1.0f + __expf(-(C2[i] + bp[i])));
            float o  = C1[i] * g + C0[i] * (1.0f - g);
            if (active) out[(size_t)prow * N_PRED + col] = o;
        }

        // ---- rotate pipeline ----
        if (r + 1 < RPW) {
            a0 = na0; a1 = na1; b0 = nb0; b1 = nb1;
            #pragma unroll
            for (int i = 0; i < 4; ++i) bp[i] = nbp[i];
        }
    }
}

extern "C" void kernel_launch(void* const* d_in, const int* in_sizes, int n_in,
                              void* d_out, int out_size, void* d_ws, size_t ws_size,
                              hipStream_t stream) {
    const float* inp      = (const float*)d_in[0];
    const float* ctrl     = (const float*)d_in[1];
    const float* offset_t = (const float*)d_in[2];
    const float* offset_n = (const float*)d_in[3];
    const float* conv_t_w = (const float*)d_in[4];
    const float* conv_t_b = (const float*)d_in[5];
    const float* conv_n_w = (const float*)d_in[6];
    const float* conv_n_b = (const float*)d_in[7];
    const float* W        = (const float*)d_in[8];
    const float* bparam   = (const float*)d_in[9];
    float* out = (float*)d_out;

    unsigned short* wsB = (unsigned short*)d_ws;   // 12288 B of fragments

    bw_probe<<<1024, 256, 0, stream>>>((const float4*)inp, out);
    deform_precompute<<<1, 256, 0, stream>>>(offset_t, offset_n,
                                             conv_t_w, conv_t_b,
                                             conv_n_w, conv_n_b, W, wsB);
    deform_main<<<NBLK, 256, 0, stream>>>(inp, ctrl, bparam, wsB, out);
}